// Round 17
// baseline (101.292 us; speedup 1.0000x reference)
//
#include <hip/hip_runtime.h>

typedef float    f32x4  __attribute__((ext_vector_type(4)));
typedef float    f32x16 __attribute__((ext_vector_type(16)));
typedef __bf16   bf16x8 __attribute__((ext_vector_type(8)));
typedef __bf16   bf16x2 __attribute__((ext_vector_type(2)));
typedef unsigned uint2v __attribute__((ext_vector_type(2)));
typedef unsigned u32x4  __attribute__((ext_vector_type(4)));

union Frag { unsigned u[4]; bf16x8 b; };

static __device__ __forceinline__ unsigned pack2(float a, float b) {
    bf16x2 t;
    t[0] = (__bf16)a;
    t[1] = (__bf16)b;
    return __builtin_bit_cast(unsigned, t);
}

// packed relu on 2xbf16 via v_pk_max_f16 (exact for reachable magnitudes)
static __device__ __forceinline__ unsigned relupk(float a, float b, unsigned zero) {
    unsigned x = pack2(a, b), r;
    asm("v_pk_max_f16 %0, %1, %2" : "=v"(r) : "v"(x), "v"(zero));
    return r;
}

static __device__ __forceinline__ unsigned short f2bfu(float x) {
    __bf16 b = (__bf16)x;
    return __builtin_bit_cast(unsigned short, b);
}

// VERIFIED convention (derived from the working L1 relayout, R1-R16):
//   pswap(a,b) -> r[0] = {low: a_low, high: b_low}
//                 r[1] = {low: a_high, high: b_high}
static __device__ __forceinline__ uint2v pswap(unsigned a, unsigned b) {
#if __has_builtin(__builtin_amdgcn_permlane32_swap)
    return __builtin_amdgcn_permlane32_swap(a, b, false, false);
#else
    unsigned ax = (unsigned)__shfl_xor((int)a, 32);
    unsigned bx = (unsigned)__shfl_xor((int)b, 32);
    bool lo = (__lane_id() & 32) == 0;
    uint2v r;
    r[0] = lo ? a : bx;
    r[1] = lo ? ax : b;
    return r;
#endif
}

// cross-half sum: s + s[lane^32] (R13-verified selection)
static __device__ __forceinline__ float xhalf_sum(float s, int half) {
    unsigned su = __builtin_bit_cast(unsigned, s);
    uint2v r = pswap(su, su);
    float other = __builtin_bit_cast(float, half ? r[0] : r[1]);
    return s + other;
}

// async global->LDS (per-lane global src; LDS dest = uniform base + lane*size)
static __device__ __forceinline__ void gll16(const void* g, void* l) {
    __builtin_amdgcn_global_load_lds(
        (const __attribute__((address_space(1))) unsigned int*)g,
        (__attribute__((address_space(3))) unsigned int*)l, 16, 0, 0);
}
static __device__ __forceinline__ void gll4(const void* g, void* l) {
    __builtin_amdgcn_global_load_lds(
        (const __attribute__((address_space(1))) unsigned int*)g,
        (__attribute__((address_space(3))) unsigned int*)l, 4, 0, 0);
}

// volatile LDS reads (defeat CSE/LICM re-materializing registers)
static __device__ __forceinline__ f32x16 ldsb16(const float* p) {
    f32x16 r;
    #pragma unroll
    for (int q = 0; q < 4; ++q) {
        f32x4 v = *((const volatile f32x4*)p + q);
        r[4 * q + 0] = v[0]; r[4 * q + 1] = v[1];
        r[4 * q + 2] = v[2]; r[4 * q + 3] = v[3];
    }
    return r;
}
static __device__ __forceinline__ bf16x8 ldsb8(const unsigned short* p) {
    u32x4 v = *(const volatile u32x4*)p;
    Frag f;
    f.u[0] = v[0]; f.u[1] = v[1]; f.u[2] = v[2]; f.u[3] = v[3];
    return f.b;
}

// ---------------------------------------------------------------------------
// Weight preprocess (320 blocks).
//  w1bf: [20][64][16] bf16 natural              (A-frag: lane 16B = 8 d)
//  w2f : [20][f][64][8] bf16, f=tg*4+kk, value = W2[m][32(f>>2)+(l&31)][16(f&3)+8(l>>5)+j]
//  b1g/b2g/w3g: [20][64] f32 in C-frag staging order:
//      value l = src[m][cmap(l)], cmap(l)=32(l>>5)+4((l>>4)&1)+(l&3)+8((l>>2)&3)
//      so LDS copy reads as [t][half][16] matching the verified C/D layout.
// ---------------------------------------------------------------------------
__global__ __launch_bounds__(256, 4) void prep_kernel(
    const float* __restrict__ W1, const float* __restrict__ W2,
    const float* __restrict__ b1, const float* __restrict__ b2,
    const float* __restrict__ W3,
    unsigned short* __restrict__ w1bf, unsigned short* __restrict__ w2f,
    float* __restrict__ b1g, float* __restrict__ b2g, float* __restrict__ w3g)
{
    const int t = blockIdx.x * 256 + threadIdx.x;
    if (t < 20480) w1bf[t] = f2bfu(W1[t]);
    if (t < 81920) {
        const int j = t & 7, l = (t >> 3) & 63, f = (t >> 9) & 7, m = t >> 12;
        const int g = 32 * (f >> 2) + (l & 31);
        const int h = 16 * (f & 3) + 8 * (l >> 5) + j;
        w2f[t] = f2bfu(W2[(m * 64 + g) * 64 + h]);
    }
    if (t < 1280) {
        const int l = t & 63, m = t >> 6;
        const int h = 32 * (l >> 5) + 4 * ((l >> 4) & 1) + (l & 3) + 8 * ((l >> 2) & 3);
        b1g[t] = b1[m * 64 + h];
        b2g[t] = b2[m * 64 + h];
        w3g[t] = W3[m * 64 + h];
    }
}

// ---------------------------------------------------------------------------
// Fused, 128 events/block, grid 1024, (256,3) -- the FIRST 3-wave bid with a
// structural register cut (prior bids R5/R9/R10/R15 only relabeled bounds and
// spilled; measured footprint was ~120 arch persistents + ~64 acc):
//  - a2 -> LDS (global_load_lds staged per m; volatile ds_read_b128 per use)
//  - biases/w3 -> LDS f32 C-frag tables (kills 48 persistent regs AND ~80
//    VALU unpack ops/tile; acc-init & L3 weights are broadcast LDS reads)
//  - xf -> shared LDS, computed once per block (waves previously duplicated)
// LDS 51 KB/block => 3 blocks/CU; estimated regs ~150 < 170 budget.
// Spill tripwire: WRITE ~33.5 MB, FETCH ~6-10 MB, VGPR <= 128.
// ---------------------------------------------------------------------------
__global__ __launch_bounds__(256, 3) void fused_kernel(
    const unsigned short* __restrict__ w1bf,
    const unsigned short* __restrict__ w2f,
    const float* __restrict__ b1g,
    const float* __restrict__ b2g,
    const float* __restrict__ w3g,
    const float* __restrict__ b3,
    const float* __restrict__ Data,
    const float* __restrict__ Shift,
    const float* __restrict__ Scaling,
    const float* __restrict__ Parameters,
    const float* __restrict__ PScal,
    float* __restrict__ rho, int N)
{
    __shared__ float          o[128][24];          // 12288 B
    __shared__ unsigned short a2l[4][8][64][8];    // 32768 B (per-wave a2 stage)
    __shared__ unsigned short xfl[4][64][8];       //  4096 B (shared x-frags)
    __shared__ float          bwl[4][3][64];       //  3072 B (b1,b2,w3 per wave)

    const int tid  = threadIdx.x;
    const int wave = tid >> 6;
    const int lane = tid & 63;
    const int ln   = lane & 31;
    const int half = lane >> 5;
    const int n0   = blockIdx.x * 128;

    unsigned zero = 0;
    asm volatile("" : "+v"(zero));   // pin 0 in a VGPR for v_pk_max_f16

    // ---- x preprocessing: each wave computes ONE shared fragment (f=wave) ----
    {
        float sh[8], is[8];
        #pragma unroll
        for (int j = 0; j < 8; ++j) {
            sh[j] = Shift[8 * half + j];
            is[j] = 1.0f / Scaling[8 * half + j];
        }
        const float* dp = Data + (size_t)(n0 + 32 * wave + ln) * 16 + 8 * half;
        f32x4 v0 = *(const f32x4*)dp;
        f32x4 v1 = *(const f32x4*)(dp + 4);
        float xv[8];
        #pragma unroll
        for (int j = 0; j < 4; ++j) {
            xv[j]     = (v0[j] - sh[j])     * is[j];
            xv[4 + j] = (v1[j] - sh[4 + j]) * is[4 + j];
        }
        u32x4 w;
        #pragma unroll
        for (int c = 0; c < 4; ++c) w[c] = pack2(xv[2 * c], xv[2 * c + 1]);
        *(u32x4*)&xfl[wave][lane][0] = w;
    }

    // ---- per-lane rho coefficients (k = lane), used after the barrier ----
    const float pk1 = Parameters[lane * 5 + 0] / PScal[0];
    const float pk2 = Parameters[lane * 5 + 1] / PScal[1];
    const float pk3 = Parameters[lane * 5 + 2] / PScal[2];
    const float pk4 = Parameters[lane * 5 + 3] / PScal[3];
    const float pk5 = Parameters[lane * 5 + 4] / PScal[4];

    __syncthreads();   // xfl visible to all waves

    // ---- MLP: 5 networks per wave, 4 tiles each ----
    #pragma unroll 1
    for (int mi = 0; mi < 5; ++mi) {
        const int m = wave * 5 + mi;

        // WAR fence: prior tiles' ds_reads of a2l/bwl must complete first
        asm volatile("s_waitcnt lgkmcnt(0)" ::: "memory");
        // stage this m's weights into per-wave LDS (async DMA)
        #pragma unroll
        for (int f = 0; f < 8; ++f)
            gll16(w2f + ((size_t)(m * 8 + f) * 64 + lane) * 8, &a2l[wave][f][0][0]);
        gll4(b1g + m * 64 + lane, &bwl[wave][0][0]);
        gll4(b2g + m * 64 + lane, &bwl[wave][1][0]);
        gll4(w3g + m * 64 + lane, &bwl[wave][2][0]);

        bf16x8 a1[2];
        #pragma unroll
        for (int t = 0; t < 2; ++t)
            a1[t] = *(const bf16x8*)(w1bf + (size_t)(m * 64 + 32 * t + ln) * 16 + 8 * half);
        const float b3v = b3[m];

        asm volatile("s_waitcnt vmcnt(0)" ::: "memory");   // staging complete

        float res[4];
        #pragma unroll
        for (int e = 0; e < 4; ++e) {
            const bf16x8 xfe = *(const bf16x8*)&xfl[e][lane][0];
            // ---- L1: acc init from LDS bias table ----
            unsigned bfr[4][4];
            #pragma unroll
            for (int t = 0; t < 2; ++t) {
                f32x16 acc = ldsb16(&bwl[wave][0][t * 32 + half * 16]);
                acc = __builtin_amdgcn_mfma_f32_32x32x16_bf16(a1[t], xfe, acc, 0, 0, 0);
                unsigned p[8];
                #pragma unroll
                for (int q = 0; q < 8; ++q)
                    p[q] = relupk(acc[2 * q], acc[2 * q + 1], zero);
                uint2v r0 = pswap(p[0], p[2]);
                uint2v r1 = pswap(p[1], p[3]);
                uint2v r2 = pswap(p[4], p[6]);
                uint2v r3 = pswap(p[5], p[7]);
                bfr[2 * t    ][0] = r0[0]; bfr[2 * t    ][1] = r1[0];
                bfr[2 * t    ][2] = r0[1]; bfr[2 * t    ][3] = r1[1];
                bfr[2 * t + 1][0] = r2[0]; bfr[2 * t + 1][1] = r3[0];
                bfr[2 * t + 1][2] = r2[1]; bfr[2 * t + 1][3] = r3[1];
            }
            // ---- L2: two independent tg-chains; a2 fragments from LDS ----
            Frag fb[4];
            #pragma unroll
            for (int kk = 0; kk < 4; ++kk)
                #pragma unroll
                for (int c = 0; c < 4; ++c) fb[kk].u[c] = bfr[kk][c];
            f32x16 ac0 = ldsb16(&bwl[wave][1][half * 16]);
            f32x16 ac1 = ldsb16(&bwl[wave][1][32 + half * 16]);
            #pragma unroll
            for (int kk = 0; kk < 4; ++kk) {
                bf16x8 a2k0 = ldsb8(&a2l[wave][kk][lane][0]);
                bf16x8 a2k1 = ldsb8(&a2l[wave][4 + kk][lane][0]);
                ac0 = __builtin_amdgcn_mfma_f32_32x32x16_bf16(a2k0, fb[kk].b, ac0, 0, 0, 0);
                ac1 = __builtin_amdgcn_mfma_f32_32x32x16_bf16(a2k1, fb[kk].b, ac1, 0, 0, 0);
            }
            // ---- L3 on VALU: w3 from LDS f32 table ----
            f32x16 w3a = ldsb16(&bwl[wave][2][half * 16]);
            f32x16 w3b = ldsb16(&bwl[wave][2][32 + half * 16]);
            float s0 = 0.f, s1 = 0.f, s2 = 0.f, s3 = 0.f;
            #pragma unroll
            for (int q = 0; q < 4; ++q) {
                s0 = fmaf(w3a[4 * q + 0], fmaxf(ac0[4 * q + 0], 0.f), s0);
                s1 = fmaf(w3a[4 * q + 1], fmaxf(ac0[4 * q + 1], 0.f), s1);
                s2 = fmaf(w3a[4 * q + 2], fmaxf(ac0[4 * q + 2], 0.f), s2);
                s3 = fmaf(w3a[4 * q + 3], fmaxf(ac0[4 * q + 3], 0.f), s3);
                s0 = fmaf(w3b[4 * q + 0], fmaxf(ac1[4 * q + 0], 0.f), s0);
                s1 = fmaf(w3b[4 * q + 1], fmaxf(ac1[4 * q + 1], 0.f), s1);
                s2 = fmaf(w3b[4 * q + 2], fmaxf(ac1[4 * q + 2], 0.f), s2);
                s3 = fmaf(w3b[4 * q + 3], fmaxf(ac1[4 * q + 3], 0.f), s3);
            }
            const float s = (s0 + s1) + (s2 + s3);
            res[e] = xhalf_sum(s, half) + b3v;
        }
        o[lane][m]      = half ? res[1] : res[0];
        o[64 + lane][m] = half ? res[3] : res[2];
    }

    __syncthreads();

    // ---- rho epilogue in-block: wave handles 32 events, k = lane ----
    #pragma unroll 4
    for (int i = 0; i < 32; ++i) {
        const int ev = wave * 32 + i;
        const f32x4* rr = (const f32x4*)&o[ev][0];   // broadcast reads
        f32x4 oa = rr[0], ob = rr[1], oc = rr[2], od = rr[3], oe = rr[4];
        float m0 = 1.0f + oa[0] * pk1 + oa[1] * pk2 + oa[2] * pk3 + oa[3] * pk4 + ob[0] * pk5;
        float m1 = ob[1] * pk1 + ob[2] * pk2 + ob[3] * pk3 + oc[0] * pk4 + oc[1] * pk5;
        float m2 = oc[2] * pk2 + oc[3] * pk3 + od[0] * pk4 + od[1] * pk5;
        float m3 = od[2] * pk3 + od[3] * pk4 + oe[0] * pk5;
        float m4 = oe[1] * pk4 + oe[2] * pk5;
        float m5 = oe[3] * pk5;
        float v = m0 * m0 + m1 * m1 + m2 * m2 + m3 * m3 + m4 * m4 + m5 * m5;
        rho[(size_t)(n0 + ev) * 64 + lane] = v;
    }
}

extern "C" void kernel_launch(void* const* d_in, const int* in_sizes, int n_in,
                              void* d_out, int out_size, void* d_ws, size_t ws_size,
                              hipStream_t stream)
{
    const float* Data   = (const float*)d_in[0];
    const float* Params = (const float*)d_in[1];
    const float* Shift  = (const float*)d_in[2];
    const float* Scal   = (const float*)d_in[3];
    const float* PScal  = (const float*)d_in[4];
    const float* W1     = (const float*)d_in[5];
    const float* b1     = (const float*)d_in[6];
    const float* W2     = (const float*)d_in[7];
    const float* b2     = (const float*)d_in[8];
    const float* W3     = (const float*)d_in[9];
    const float* b3     = (const float*)d_in[10];
    float* rho = (float*)d_out;
    const int N = in_sizes[0] / 16;   // 131072

    char* ws = (char*)d_ws;
    unsigned short* w1bf = (unsigned short*)(ws);             //      0 .. 40960
    unsigned short* w2f  = (unsigned short*)(ws + 40960);     //  40960 .. 204800
    float*          b1g  = (float*)(ws + 204800);             // 204800 .. 209920
    float*          b2g  = (float*)(ws + 209920);             // 209920 .. 215040
    float*          w3g  = (float*)(ws + 215040);             // 215040 .. 220160

    prep_kernel<<<320, 256, 0, stream>>>(W1, W2, b1, b2, W3, w1bf, w2f, b1g, b2g, w3g);
    fused_kernel<<<N / 128, 256, 0, stream>>>(w1bf, w2f, b1g, b2g, w3g, b3,
                                              Data, Shift, Scal, Params, PScal, rho, N);
}

// Round 18
// 57.639 us; speedup vs baseline: 1.7573x; 1.7573x over previous
//
#include <hip/hip_runtime.h>

typedef float    f32x4  __attribute__((ext_vector_type(4)));
typedef float    f32x16 __attribute__((ext_vector_type(16)));
typedef __bf16   bf16x8 __attribute__((ext_vector_type(8)));
typedef __bf16   bf16x2 __attribute__((ext_vector_type(2)));
typedef unsigned uint2v __attribute__((ext_vector_type(2)));
typedef unsigned u32x4  __attribute__((ext_vector_type(4)));

union Frag { unsigned u[4]; bf16x8 b; };

static __device__ __forceinline__ unsigned pack2(float a, float b) {
    bf16x2 t;
    t[0] = (__bf16)a;
    t[1] = (__bf16)b;
    return __builtin_bit_cast(unsigned, t);
}

// packed relu on 2xbf16 via v_pk_max_f16 (exact for reachable magnitudes)
static __device__ __forceinline__ unsigned relupk(float a, float b, unsigned zero) {
    unsigned x = pack2(a, b), r;
    asm("v_pk_max_f16 %0, %1, %2" : "=v"(r) : "v"(x), "v"(zero));
    return r;
}

static __device__ __forceinline__ unsigned short f2bfu(float x) {
    __bf16 b = (__bf16)x;
    return __builtin_bit_cast(unsigned short, b);
}

// unpack packed-bf16 dword -> two f32 (lo element, hi element)
static __device__ __forceinline__ float bflo(unsigned u) { return __builtin_bit_cast(float, u << 16); }
static __device__ __forceinline__ float bfhi(unsigned u) { return __builtin_bit_cast(float, u & 0xffff0000u); }

// VERIFIED convention (derived from the working L1 relayout, R1-R17):
//   pswap(a,b) -> r[0] = {low: a_low, high: b_low}
//                 r[1] = {low: a_high, high: b_high}
static __device__ __forceinline__ uint2v pswap(unsigned a, unsigned b) {
#if __has_builtin(__builtin_amdgcn_permlane32_swap)
    return __builtin_amdgcn_permlane32_swap(a, b, false, false);
#else
    unsigned ax = (unsigned)__shfl_xor((int)a, 32);
    unsigned bx = (unsigned)__shfl_xor((int)b, 32);
    bool lo = (__lane_id() & 32) == 0;
    uint2v r;
    r[0] = lo ? a : bx;
    r[1] = lo ? ax : b;
    return r;
#endif
}

// cross-half sum: s + s[lane^32] (R13-verified selection)
static __device__ __forceinline__ float xhalf_sum(float s, int half) {
    unsigned su = __builtin_bit_cast(unsigned, s);
    uint2v r = pswap(su, su);
    float other = __builtin_bit_cast(float, half ? r[0] : r[1]);
    return s + other;
}

// ---------------------------------------------------------------------------
// Weight preprocess only (320 blocks).
//  w1bf: [20][64][16] bf16 natural              (A-frag: lane 16B = 8 d)
//  w2f : [20][f][64][8] bf16, f=tg*4+kk, value = W2[m][32(f>>2)+(l&31)][16(f&3)+8(l>>5)+j]
//  b1p/b2p/w3p: [20][t][half][8] packed bf16 pairs in C-frag order:
//           dword q = pack(v[h0], v[h0+1]),  h0 = 32t + 4*half + (2q&3) + 8*(2q>>2)
// ---------------------------------------------------------------------------
__global__ __launch_bounds__(256, 4) void prep_kernel(
    const float* __restrict__ W1, const float* __restrict__ W2,
    const float* __restrict__ b1, const float* __restrict__ b2,
    const float* __restrict__ W3,
    unsigned short* __restrict__ w1bf, unsigned short* __restrict__ w2f,
    unsigned* __restrict__ b1p, unsigned* __restrict__ b2p,
    unsigned* __restrict__ w3p)
{
    const int t = blockIdx.x * 256 + threadIdx.x;
    if (t < 20480) w1bf[t] = f2bfu(W1[t]);
    if (t < 81920) {
        const int j = t & 7, l = (t >> 3) & 63, f = (t >> 9) & 7, m = t >> 12;
        const int g = 32 * (f >> 2) + (l & 31);
        const int h = 16 * (f & 3) + 8 * (l >> 5) + j;
        w2f[t] = f2bfu(W2[(m * 64 + g) * 64 + h]);
    }
    if (t < 640) {
        const int q = t & 7, hf = (t >> 3) & 1, tt = (t >> 4) & 1, m = t >> 5;
        const int h0 = 32 * tt + 4 * hf + ((2 * q) & 3) + 8 * ((2 * q) >> 2);
        b1p[t] = pack2(b1[m * 64 + h0], b1[m * 64 + h0 + 1]);
        b2p[t] = pack2(b2[m * 64 + h0], b2[m * 64 + h0 + 1]);
        w3p[t] = pack2(W3[m * 64 + h0], W3[m * 64 + h0 + 1]);
    }
}

// ---------------------------------------------------------------------------
// Fused, 256 events/block, (256,2) -- EXACT R14 structure (best measured:
// 55.8us kernel), which R16 (2-way pairing: spilled) and R17 (LDS offload:
// ds_read latency on critical path, 104us) both failed to beat. Occupancy
// ladder closed: every 3+-wave bid spills (R5/R9/R10/R15).
// Single new variable vs R14: s_setprio(1)/(0) around MFMA regions (T5).
// Mechanism requires wave phase-diversity on the SIMD -- this kernel's
// m-loop has NO barriers, so co-resident waves drift into different phases
// (L1-pack / L2-MFMA / L3-VALU), giving the CU scheduler real arbitration
// choices (attn analogue: +4-7%; lockstep GEMM: null).
// Spill tripwire: WRITE ~33.5 MB, FETCH ~5 MB.
// ---------------------------------------------------------------------------
__global__ __launch_bounds__(256, 2) void fused_kernel(
    const unsigned short* __restrict__ w1bf,
    const unsigned short* __restrict__ w2f,
    const unsigned* __restrict__ b1p,
    const unsigned* __restrict__ b2p,
    const unsigned* __restrict__ w3p,
    const float* __restrict__ b3,
    const float* __restrict__ Data,
    const float* __restrict__ Shift,
    const float* __restrict__ Scaling,
    const float* __restrict__ Parameters,
    const float* __restrict__ PScal,
    float* __restrict__ rho, int N)
{
    __shared__ float o[256][24];   // [event][network]; 96B rows (16B-aligned)

    const int tid  = threadIdx.x;
    const int wave = tid >> 6;
    const int lane = tid & 63;
    const int ln   = lane & 31;
    const int half = lane >> 5;
    const int n0   = blockIdx.x * 256;

    unsigned zero = 0;
    asm volatile("" : "+v"(zero));   // pin 0 in a VGPR for v_pk_max_f16

    // ---- inline x preprocessing: 8 bf16 B-fragments (32 regs) ----
    bf16x8 xf[8];
    {
        float sh[8], is[8];
        #pragma unroll
        for (int j = 0; j < 8; ++j) {
            sh[j] = Shift[8 * half + j];
            is[j] = 1.0f / Scaling[8 * half + j];
        }
        #pragma unroll
        for (int f = 0; f < 8; ++f) {
            const float* dp = Data + (size_t)(n0 + 32 * f + ln) * 16 + 8 * half;
            f32x4 v0 = *(const f32x4*)dp;
            f32x4 v1 = *(const f32x4*)(dp + 4);
            float xv[8];
            #pragma unroll
            for (int j = 0; j < 4; ++j) {
                xv[j]     = (v0[j] - sh[j])     * is[j];
                xv[4 + j] = (v1[j] - sh[4 + j]) * is[4 + j];
            }
            Frag fx;
            #pragma unroll
            for (int c = 0; c < 4; ++c) fx.u[c] = pack2(xv[2 * c], xv[2 * c + 1]);
            xf[f] = fx.b;
        }
    }

    // ---- per-lane rho coefficients (k = lane), used after the barrier ----
    const float pk1 = Parameters[lane * 5 + 0] / PScal[0];
    const float pk2 = Parameters[lane * 5 + 1] / PScal[1];
    const float pk3 = Parameters[lane * 5 + 2] / PScal[2];
    const float pk4 = Parameters[lane * 5 + 3] / PScal[3];
    const float pk5 = Parameters[lane * 5 + 4] / PScal[4];

    // ---- MLP: 5 networks per wave, 8 event-tiles each ----
    for (int mi = 0; mi < 5; ++mi) {
        const int m = wave * 5 + mi;
        bf16x8 a1[2];
        #pragma unroll
        for (int t = 0; t < 2; ++t)
            a1[t] = *(const bf16x8*)(w1bf + (size_t)(m * 64 + 32 * t + ln) * 16 + 8 * half);
        bf16x8 a2[8];
        #pragma unroll
        for (int f = 0; f < 8; ++f)
            a2[f] = *(const bf16x8*)(w2f + (size_t)((m * 8 + f) * 64 + lane) * 8);
        u32x4 w3u[2][2], b1r[2][2], b2r[2][2];
        #pragma unroll
        for (int t = 0; t < 2; ++t) {
            const unsigned* p1 = b1p + ((m * 2 + t) * 2 + half) * 8;
            b1r[t][0] = *(const u32x4*)p1;
            b1r[t][1] = *(const u32x4*)(p1 + 4);
            const unsigned* p2 = b2p + ((m * 2 + t) * 2 + half) * 8;
            b2r[t][0] = *(const u32x4*)p2;
            b2r[t][1] = *(const u32x4*)(p2 + 4);
            const unsigned* p3 = w3p + ((m * 2 + t) * 2 + half) * 8;
            w3u[t][0] = *(const u32x4*)p3;
            w3u[t][1] = *(const u32x4*)(p3 + 4);
        }
        const float b3v = b3[m];

        #pragma unroll
        for (int it = 0; it < 2; ++it) {
            float res[4];
            #pragma unroll
            for (int e = 0; e < 4; ++e) {
                const bf16x8 xfe = xf[it * 4 + e];
                // ---- L1 ----
                unsigned bfr[4][4];
                #pragma unroll
                for (int t = 0; t < 2; ++t) {
                    f32x16 acc;
                    #pragma unroll
                    for (int hq = 0; hq < 2; ++hq)
                        #pragma unroll
                        for (int q4 = 0; q4 < 4; ++q4) {
                            const unsigned u = b1r[t][hq][q4];
                            acc[8 * hq + 2 * q4]     = bflo(u);
                            acc[8 * hq + 2 * q4 + 1] = bfhi(u);
                        }
                    __builtin_amdgcn_s_setprio(1);
                    acc = __builtin_amdgcn_mfma_f32_32x32x16_bf16(a1[t], xfe, acc, 0, 0, 0);
                    __builtin_amdgcn_s_setprio(0);
                    unsigned p[8];
                    #pragma unroll
                    for (int q = 0; q < 8; ++q)
                        p[q] = relupk(acc[2 * q], acc[2 * q + 1], zero);
                    uint2v r0 = pswap(p[0], p[2]);
                    uint2v r1 = pswap(p[1], p[3]);
                    uint2v r2 = pswap(p[4], p[6]);
                    uint2v r3 = pswap(p[5], p[7]);
                    bfr[2 * t    ][0] = r0[0]; bfr[2 * t    ][1] = r1[0];
                    bfr[2 * t    ][2] = r0[1]; bfr[2 * t    ][3] = r1[1];
                    bfr[2 * t + 1][0] = r2[0]; bfr[2 * t + 1][1] = r3[0];
                    bfr[2 * t + 1][2] = r2[1]; bfr[2 * t + 1][3] = r3[1];
                }
                // ---- L2: two independent tg-chains, interleaved ----
                Frag fb[4];
                #pragma unroll
                for (int kk = 0; kk < 4; ++kk)
                    #pragma unroll
                    for (int c = 0; c < 4; ++c) fb[kk].u[c] = bfr[kk][c];
                f32x16 ac0, ac1;
                #pragma unroll
                for (int hq = 0; hq < 2; ++hq)
                    #pragma unroll
                    for (int q4 = 0; q4 < 4; ++q4) {
                        const unsigned u0 = b2r[0][hq][q4];
                        const unsigned u1 = b2r[1][hq][q4];
                        ac0[8 * hq + 2 * q4]     = bflo(u0);
                        ac0[8 * hq + 2 * q4 + 1] = bfhi(u0);
                        ac1[8 * hq + 2 * q4]     = bflo(u1);
                        ac1[8 * hq + 2 * q4 + 1] = bfhi(u1);
                    }
                __builtin_amdgcn_s_setprio(1);
                #pragma unroll
                for (int kk = 0; kk < 4; ++kk) {
                    ac0 = __builtin_amdgcn_mfma_f32_32x32x16_bf16(a2[kk],     fb[kk].b, ac0, 0, 0, 0);
                    ac1 = __builtin_amdgcn_mfma_f32_32x32x16_bf16(a2[4 + kk], fb[kk].b, ac1, 0, 0, 0);
                }
                __builtin_amdgcn_s_setprio(0);
                // ---- L3 on VALU (packed w3, unpack per use) ----
                float s0 = 0.f, s1 = 0.f, s2 = 0.f, s3 = 0.f;
                #pragma unroll
                for (int q = 0; q < 4; ++q) {
                    const unsigned da = w3u[0][q >> 1][(2 * q) & 3];
                    const unsigned db = w3u[0][q >> 1][(2 * q + 1) & 3];
                    const unsigned dc = w3u[1][q >> 1][(2 * q) & 3];
                    const unsigned dd = w3u[1][q >> 1][(2 * q + 1) & 3];
                    s0 = fmaf(bflo(da), fmaxf(ac0[4 * q + 0], 0.f), s0);
                    s1 = fmaf(bfhi(da), fmaxf(ac0[4 * q + 1], 0.f), s1);
                    s2 = fmaf(bflo(db), fmaxf(ac0[4 * q + 2], 0.f), s2);
                    s3 = fmaf(bfhi(db), fmaxf(ac0[4 * q + 3], 0.f), s3);
                    s0 = fmaf(bflo(dc), fmaxf(ac1[4 * q + 0], 0.f), s0);
                    s1 = fmaf(bfhi(dc), fmaxf(ac1[4 * q + 1], 0.f), s1);
                    s2 = fmaf(bflo(dd), fmaxf(ac1[4 * q + 2], 0.f), s2);
                    s3 = fmaf(bfhi(dd), fmaxf(ac1[4 * q + 3], 0.f), s3);
                }
                const float s = (s0 + s1) + (s2 + s3);
                res[e] = xhalf_sum(s, half) + b3v;
            }
            o[it * 128 + lane][m]      = half ? res[1] : res[0];
            o[it * 128 + 64 + lane][m] = half ? res[3] : res[2];
        }
    }

    __syncthreads();

    // ---- rho epilogue in-block: wave handles 64 events, k = lane ----
    #pragma unroll 4
    for (int i = 0; i < 64; ++i) {
        const int ev = wave * 64 + i;
        const f32x4* rr = (const f32x4*)&o[ev][0];   // broadcast reads
        f32x4 oa = rr[0], ob = rr[1], oc = rr[2], od = rr[3], oe = rr[4];
        float m0 = 1.0f + oa[0] * pk1 + oa[1] * pk2 + oa[2] * pk3 + oa[3] * pk4 + ob[0] * pk5;
        float m1 = ob[1] * pk1 + ob[2] * pk2 + ob[3] * pk3 + oc[0] * pk4 + oc[1] * pk5;
        float m2 = oc[2] * pk2 + oc[3] * pk3 + od[0] * pk4 + od[1] * pk5;
        float m3 = od[2] * pk3 + od[3] * pk4 + oe[0] * pk5;
        float m4 = oe[1] * pk4 + oe[2] * pk5;
        float m5 = oe[3] * pk5;
        float v = m0 * m0 + m1 * m1 + m2 * m2 + m3 * m3 + m4 * m4 + m5 * m5;
        rho[(size_t)(n0 + ev) * 64 + lane] = v;
    }
}

extern "C" void kernel_launch(void* const* d_in, const int* in_sizes, int n_in,
                              void* d_out, int out_size, void* d_ws, size_t ws_size,
                              hipStream_t stream)
{
    const float* Data   = (const float*)d_in[0];
    const float* Params = (const float*)d_in[1];
    const float* Shift  = (const float*)d_in[2];
    const float* Scal   = (const float*)d_in[3];
    const float* PScal  = (const float*)d_in[4];
    const float* W1     = (const float*)d_in[5];
    const float* b1     = (const float*)d_in[6];
    const float* W2     = (const float*)d_in[7];
    const float* b2     = (const float*)d_in[8];
    const float* W3     = (const float*)d_in[9];
    const float* b3     = (const float*)d_in[10];
    float* rho = (float*)d_out;
    const int N = in_sizes[0] / 16;   // 131072

    char* ws = (char*)d_ws;
    unsigned short* w1bf = (unsigned short*)(ws);             //      0 .. 40960
    unsigned short* w2f  = (unsigned short*)(ws + 40960);     //  40960 .. 204800
    unsigned*       b1p  = (unsigned*)(ws + 204800);          // 204800 .. 207360
    unsigned*       b2p  = (unsigned*)(ws + 207360);          // 207360 .. 209920
    unsigned*       w3p  = (unsigned*)(ws + 209920);          // 209920 .. 212480

    prep_kernel<<<320, 256, 0, stream>>>(W1, W2, b1, b2, W3, w1bf, w2f, b1p, b2p, w3p);
    fused_kernel<<<N / 256, 256, 0, stream>>>(w1bf, w2f, b1p, b2p, w3p, b3,
                                              Data, Shift, Scal, Params, PScal, rho, N);
}

// Round 19
// 56.497 us; speedup vs baseline: 1.7929x; 1.0202x over previous
//
#include <hip/hip_runtime.h>

typedef float    f32x4  __attribute__((ext_vector_type(4)));
typedef float    f32x16 __attribute__((ext_vector_type(16)));
typedef __bf16   bf16x8 __attribute__((ext_vector_type(8)));
typedef __bf16   bf16x2 __attribute__((ext_vector_type(2)));
typedef unsigned uint2v __attribute__((ext_vector_type(2)));
typedef unsigned u32x4  __attribute__((ext_vector_type(4)));

union Frag { unsigned u[4]; bf16x8 b; };

static __device__ __forceinline__ unsigned pack2(float a, float b) {
    bf16x2 t;
    t[0] = (__bf16)a;
    t[1] = (__bf16)b;
    return __builtin_bit_cast(unsigned, t);
}

// packed relu on 2xbf16 via v_pk_max_f16 (exact for reachable magnitudes)
static __device__ __forceinline__ unsigned relupk(float a, float b, unsigned zero) {
    unsigned x = pack2(a, b), r;
    asm("v_pk_max_f16 %0, %1, %2" : "=v"(r) : "v"(x), "v"(zero));
    return r;
}

static __device__ __forceinline__ unsigned short f2bfu(float x) {
    __bf16 b = (__bf16)x;
    return __builtin_bit_cast(unsigned short, b);
}

// unpack packed-bf16 dword -> two f32 (lo element, hi element)
static __device__ __forceinline__ float bflo(unsigned u) { return __builtin_bit_cast(float, u << 16); }
static __device__ __forceinline__ float bfhi(unsigned u) { return __builtin_bit_cast(float, u & 0xffff0000u); }

// VERIFIED convention (derived from the working L1 relayout, R1-R18):
//   pswap(a,b) -> r[0] = {low: a_low, high: b_low}
//                 r[1] = {low: a_high, high: b_high}
static __device__ __forceinline__ uint2v pswap(unsigned a, unsigned b) {
#if __has_builtin(__builtin_amdgcn_permlane32_swap)
    return __builtin_amdgcn_permlane32_swap(a, b, false, false);
#else
    unsigned ax = (unsigned)__shfl_xor((int)a, 32);
    unsigned bx = (unsigned)__shfl_xor((int)b, 32);
    bool lo = (__lane_id() & 32) == 0;
    uint2v r;
    r[0] = lo ? a : bx;
    r[1] = lo ? ax : b;
    return r;
#endif
}

// cross-half sum: s + s[lane^32] (R13-verified selection)
static __device__ __forceinline__ float xhalf_sum(float s, int half) {
    unsigned su = __builtin_bit_cast(unsigned, s);
    uint2v r = pswap(su, su);
    float other = __builtin_bit_cast(float, half ? r[0] : r[1]);
    return s + other;
}

// ---------------------------------------------------------------------------
// Weight preprocess only (320 blocks).
//  w1bf: [20][64][16] bf16 natural              (A-frag: lane 16B = 8 d)
//  w2f : [20][f][64][8] bf16, f=tg*4+kk, value = W2[m][32(f>>2)+(l&31)][16(f&3)+8(l>>5)+j]
//  b1p/b2p/w3p: [20][t][half][8] packed bf16 pairs in C-frag order:
//           dword q = pack(v[h0], v[h0+1]),  h0 = 32t + 4*half + (2q&3) + 8*(2q>>2)
// ---------------------------------------------------------------------------
__global__ __launch_bounds__(256, 4) void prep_kernel(
    const float* __restrict__ W1, const float* __restrict__ W2,
    const float* __restrict__ b1, const float* __restrict__ b2,
    const float* __restrict__ W3,
    unsigned short* __restrict__ w1bf, unsigned short* __restrict__ w2f,
    unsigned* __restrict__ b1p, unsigned* __restrict__ b2p,
    unsigned* __restrict__ w3p)
{
    const int t = blockIdx.x * 256 + threadIdx.x;
    if (t < 20480) w1bf[t] = f2bfu(W1[t]);
    if (t < 81920) {
        const int j = t & 7, l = (t >> 3) & 63, f = (t >> 9) & 7, m = t >> 12;
        const int g = 32 * (f >> 2) + (l & 31);
        const int h = 16 * (f & 3) + 8 * (l >> 5) + j;
        w2f[t] = f2bfu(W2[(m * 64 + g) * 64 + h]);
    }
    if (t < 640) {
        const int q = t & 7, hf = (t >> 3) & 1, tt = (t >> 4) & 1, m = t >> 5;
        const int h0 = 32 * tt + 4 * hf + ((2 * q) & 3) + 8 * ((2 * q) >> 2);
        b1p[t] = pack2(b1[m * 64 + h0], b1[m * 64 + h0 + 1]);
        b2p[t] = pack2(b2[m * 64 + h0], b2[m * 64 + h0 + 1]);
        w3p[t] = pack2(W3[m * 64 + h0], W3[m * 64 + h0 + 1]);
    }
}

// ---------------------------------------------------------------------------
// Fused, 256 events/block, (256,2) -- R14 structure (best: 55.8us kernel).
// Single variable vs R14: bias/w3 unpacked ONCE per m into f32 registers,
// PINNED via asm volatile (opaque def point -> compiler cannot rematerialize,
// which is how it silently defeated R7's hoist), then passed directly as the
// MFMA C operand (D != C legal) and as L3 weights. Deletes ~80 redundant
// VALU ops/tile (~17% of the VALU stream). Persistents ~185, peak ~240 <
// 256. KEY diagnostic: VGPR_Count 170-210 = hoist held; ~120 = defeated.
// Spill tripwire: WRITE ~33.5 MB, FETCH ~5 MB.
// ---------------------------------------------------------------------------
__global__ __launch_bounds__(256, 2) void fused_kernel(
    const unsigned short* __restrict__ w1bf,
    const unsigned short* __restrict__ w2f,
    const unsigned* __restrict__ b1p,
    const unsigned* __restrict__ b2p,
    const unsigned* __restrict__ w3p,
    const float* __restrict__ b3,
    const float* __restrict__ Data,
    const float* __restrict__ Shift,
    const float* __restrict__ Scaling,
    const float* __restrict__ Parameters,
    const float* __restrict__ PScal,
    float* __restrict__ rho, int N)
{
    __shared__ float o[256][24];   // [event][network]; 96B rows (16B-aligned)

    const int tid  = threadIdx.x;
    const int wave = tid >> 6;
    const int lane = tid & 63;
    const int ln   = lane & 31;
    const int half = lane >> 5;
    const int n0   = blockIdx.x * 256;

    unsigned zero = 0;
    asm volatile("" : "+v"(zero));   // pin 0 in a VGPR for v_pk_max_f16

    // ---- inline x preprocessing: 8 bf16 B-fragments (32 regs) ----
    bf16x8 xf[8];
    {
        float sh[8], is[8];
        #pragma unroll
        for (int j = 0; j < 8; ++j) {
            sh[j] = Shift[8 * half + j];
            is[j] = 1.0f / Scaling[8 * half + j];
        }
        #pragma unroll
        for (int f = 0; f < 8; ++f) {
            const float* dp = Data + (size_t)(n0 + 32 * f + ln) * 16 + 8 * half;
            f32x4 v0 = *(const f32x4*)dp;
            f32x4 v1 = *(const f32x4*)(dp + 4);
            float xv[8];
            #pragma unroll
            for (int j = 0; j < 4; ++j) {
                xv[j]     = (v0[j] - sh[j])     * is[j];
                xv[4 + j] = (v1[j] - sh[4 + j]) * is[4 + j];
            }
            Frag fx;
            #pragma unroll
            for (int c = 0; c < 4; ++c) fx.u[c] = pack2(xv[2 * c], xv[2 * c + 1]);
            xf[f] = fx.b;
        }
    }

    // ---- per-lane rho coefficients (k = lane), used after the barrier ----
    const float pk1 = Parameters[lane * 5 + 0] / PScal[0];
    const float pk2 = Parameters[lane * 5 + 1] / PScal[1];
    const float pk3 = Parameters[lane * 5 + 2] / PScal[2];
    const float pk4 = Parameters[lane * 5 + 3] / PScal[3];
    const float pk5 = Parameters[lane * 5 + 4] / PScal[4];

    // ---- MLP: 5 networks per wave, 8 event-tiles each ----
    for (int mi = 0; mi < 5; ++mi) {
        const int m = wave * 5 + mi;
        bf16x8 a1[2];
        #pragma unroll
        for (int t = 0; t < 2; ++t)
            a1[t] = *(const bf16x8*)(w1bf + (size_t)(m * 64 + 32 * t + ln) * 16 + 8 * half);
        bf16x8 a2[8];
        #pragma unroll
        for (int f = 0; f < 8; ++f)
            a2[f] = *(const bf16x8*)(w2f + (size_t)((m * 8 + f) * 64 + lane) * 8);
        const float b3v = b3[m];

        // ---- unpack biases/w3 ONCE per m; pin so they can't rematerialize ----
        f32x16 B1F[2], B2F[2], W3F[2];
        #pragma unroll
        for (int t = 0; t < 2; ++t) {
            const unsigned* p1 = b1p + ((m * 2 + t) * 2 + half) * 8;
            const unsigned* p2 = b2p + ((m * 2 + t) * 2 + half) * 8;
            const unsigned* p3 = w3p + ((m * 2 + t) * 2 + half) * 8;
            #pragma unroll
            for (int q = 0; q < 8; ++q) {
                const unsigned u1 = p1[q], u2 = p2[q], u3 = p3[q];
                B1F[t][2 * q] = bflo(u1); B1F[t][2 * q + 1] = bfhi(u1);
                B2F[t][2 * q] = bflo(u2); B2F[t][2 * q + 1] = bfhi(u2);
                W3F[t][2 * q] = bflo(u3); W3F[t][2 * q + 1] = bfhi(u3);
            }
        }
        #pragma unroll
        for (int i = 0; i < 16; ++i)
            asm volatile("" : "+v"(B1F[0][i]), "+v"(B1F[1][i]),
                              "+v"(B2F[0][i]), "+v"(B2F[1][i]),
                              "+v"(W3F[0][i]), "+v"(W3F[1][i]));

        #pragma unroll
        for (int it = 0; it < 2; ++it) {
            float res[4];
            #pragma unroll
            for (int e = 0; e < 4; ++e) {
                const bf16x8 xfe = xf[it * 4 + e];
                // ---- L1: pinned bias registers directly as C ----
                unsigned bfr[4][4];
                #pragma unroll
                for (int t = 0; t < 2; ++t) {
                    f32x16 acc = __builtin_amdgcn_mfma_f32_32x32x16_bf16(a1[t], xfe, B1F[t], 0, 0, 0);
                    unsigned p[8];
                    #pragma unroll
                    for (int q = 0; q < 8; ++q)
                        p[q] = relupk(acc[2 * q], acc[2 * q + 1], zero);
                    uint2v r0 = pswap(p[0], p[2]);
                    uint2v r1 = pswap(p[1], p[3]);
                    uint2v r2 = pswap(p[4], p[6]);
                    uint2v r3 = pswap(p[5], p[7]);
                    bfr[2 * t    ][0] = r0[0]; bfr[2 * t    ][1] = r1[0];
                    bfr[2 * t    ][2] = r0[1]; bfr[2 * t    ][3] = r1[1];
                    bfr[2 * t + 1][0] = r2[0]; bfr[2 * t + 1][1] = r3[0];
                    bfr[2 * t + 1][2] = r2[1]; bfr[2 * t + 1][3] = r3[1];
                }
                // ---- L2: two independent tg-chains, C = pinned bias ----
                Frag fb[4];
                #pragma unroll
                for (int kk = 0; kk < 4; ++kk)
                    #pragma unroll
                    for (int c = 0; c < 4; ++c) fb[kk].u[c] = bfr[kk][c];
                f32x16 ac0 = __builtin_amdgcn_mfma_f32_32x32x16_bf16(a2[0], fb[0].b, B2F[0], 0, 0, 0);
                f32x16 ac1 = __builtin_amdgcn_mfma_f32_32x32x16_bf16(a2[4], fb[0].b, B2F[1], 0, 0, 0);
                #pragma unroll
                for (int kk = 1; kk < 4; ++kk) {
                    ac0 = __builtin_amdgcn_mfma_f32_32x32x16_bf16(a2[kk],     fb[kk].b, ac0, 0, 0, 0);
                    ac1 = __builtin_amdgcn_mfma_f32_32x32x16_bf16(a2[4 + kk], fb[kk].b, ac1, 0, 0, 0);
                }
                // ---- L3 on VALU: pinned f32 w3 ----
                float s0 = 0.f, s1 = 0.f, s2 = 0.f, s3 = 0.f;
                #pragma unroll
                for (int q = 0; q < 4; ++q) {
                    s0 = fmaf(W3F[0][4 * q + 0], fmaxf(ac0[4 * q + 0], 0.f), s0);
                    s1 = fmaf(W3F[0][4 * q + 1], fmaxf(ac0[4 * q + 1], 0.f), s1);
                    s2 = fmaf(W3F[0][4 * q + 2], fmaxf(ac0[4 * q + 2], 0.f), s2);
                    s3 = fmaf(W3F[0][4 * q + 3], fmaxf(ac0[4 * q + 3], 0.f), s3);
                    s0 = fmaf(W3F[1][4 * q + 0], fmaxf(ac1[4 * q + 0], 0.f), s0);
                    s1 = fmaf(W3F[1][4 * q + 1], fmaxf(ac1[4 * q + 1], 0.f), s1);
                    s2 = fmaf(W3F[1][4 * q + 2], fmaxf(ac1[4 * q + 2], 0.f), s2);
                    s3 = fmaf(W3F[1][4 * q + 3], fmaxf(ac1[4 * q + 3], 0.f), s3);
                }
                const float s = (s0 + s1) + (s2 + s3);
                res[e] = xhalf_sum(s, half) + b3v;
            }
            o[it * 128 + lane][m]      = half ? res[1] : res[0];
            o[it * 128 + 64 + lane][m] = half ? res[3] : res[2];
        }
    }

    __syncthreads();

    // ---- rho epilogue in-block: wave handles 64 events, k = lane ----
    #pragma unroll 4
    for (int i = 0; i < 64; ++i) {
        const int ev = wave * 64 + i;
        const f32x4* rr = (const f32x4*)&o[ev][0];   // broadcast reads
        f32x4 oa = rr[0], ob = rr[1], oc = rr[2], od = rr[3], oe = rr[4];
        float m0 = 1.0f + oa[0] * pk1 + oa[1] * pk2 + oa[2] * pk3 + oa[3] * pk4 + ob[0] * pk5;
        float m1 = ob[1] * pk1 + ob[2] * pk2 + ob[3] * pk3 + oc[0] * pk4 + oc[1] * pk5;
        float m2 = oc[2] * pk2 + oc[3] * pk3 + od[0] * pk4 + od[1] * pk5;
        float m3 = od[2] * pk3 + od[3] * pk4 + oe[0] * pk5;
        float m4 = oe[1] * pk4 + oe[2] * pk5;
        float m5 = oe[3] * pk5;
        float v = m0 * m0 + m1 * m1 + m2 * m2 + m3 * m3 + m4 * m4 + m5 * m5;
        rho[(size_t)(n0 + ev) * 64 + lane] = v;
    }
}

extern "C" void kernel_launch(void* const* d_in, const int* in_sizes, int n_in,
                              void* d_out, int out_size, void* d_ws, size_t ws_size,
                              hipStream_t stream)
{
    const float* Data   = (const float*)d_in[0];
    const float* Params = (const float*)d_in[1];
    const float* Shift  = (const float*)d_in[2];
    const float* Scal   = (const float*)d_in[3];
    const float* PScal  = (const float*)d_in[4];
    const float* W1     = (const float*)d_in[5];
    const float* b1     = (const float*)d_in[6];
    const float* W2     = (const float*)d_in[7];
    const float* b2     = (const float*)d_in[8];
    const float* W3     = (const float*)d_in[9];
    const float* b3     = (const float*)d_in[10];
    float* rho = (float*)d_out;
    const int N = in_sizes[0] / 16;   // 131072

    char* ws = (char*)d_ws;
    unsigned short* w1bf = (unsigned short*)(ws);             //      0 .. 40960
    unsigned short* w2f  = (unsigned short*)(ws + 40960);     //  40960 .. 204800
    unsigned*       b1p  = (unsigned*)(ws + 204800);          // 204800 .. 207360
    unsigned*       b2p  = (unsigned*)(ws + 207360);          // 207360 .. 209920
    unsigned*       w3p  = (unsigned*)(ws + 209920);          // 209920 .. 212480

    prep_kernel<<<320, 256, 0, stream>>>(W1, W2, b1, b2, W3, w1bf, w2f, b1p, b2p, w3p);
    fused_kernel<<<N / 256, 256, 0, stream>>>(w1bf, w2f, b1p, b2p, w3p, b3,
                                              Data, Shift, Scal, Params, PScal, rho, N);
}